// Round 14
// baseline (64.122 us; speedup 1.0000x reference)
//
#include <hip/hip_runtime.h>
#include <hip/hip_bf16.h>

typedef __bf16 bf16x8 __attribute__((ext_vector_type(8)));
typedef float  f32x4  __attribute__((ext_vector_type(4)));

#define LRELU_ALPHA 0.2f
#define LOG2E 1.44269504088896340736f

// native 2^x (single v_exp_f32, no OCML call)
__device__ __forceinline__ float fexp2(float x) {
#if __has_builtin(__builtin_amdgcn_exp2f)
    return __builtin_amdgcn_exp2f(x);
#else
    float r; asm("v_exp_f32 %0, %1" : "=v"(r) : "v"(x)); return r;
#endif
}

// raw barrier: drains LDS (lgkmcnt) but leaves global prefetches (vmcnt) in flight
__device__ __forceinline__ void wg_barrier() {
    asm volatile("s_waitcnt lgkmcnt(0)" ::: "memory");
    __builtin_amdgcn_s_barrier();
    asm volatile("" ::: "memory");
}

// ---------------------------------------------------------------------------
// Kernel 1: h = inp @ W (8 rows/block) -> hb (bf16), f1 = log2e*(h·a1),
// f2 = log2e*(h·a2).
// ---------------------------------------------------------------------------
__global__ __launch_bounds__(128) void gat_prep(
    const float* __restrict__ inp, const float* __restrict__ W,
    const float* __restrict__ a,
    __bf16* __restrict__ hb, float* __restrict__ f1, float* __restrict__ f2)
{
    const int r0 = blockIdx.x << 3;
    const int d  = threadIdx.x;
    __shared__ float sIn[8][128];
    __shared__ float sRed[8][4];
    #pragma unroll
    for (int r = 0; r < 8; ++r)
        sIn[r][d] = inp[(size_t)(r0 + r) * 128 + d];
    __syncthreads();

    float acc[8] = {0.f,0.f,0.f,0.f,0.f,0.f,0.f,0.f};
    #pragma unroll 4
    for (int k = 0; k < 128; ++k) {
        float wv = W[k * 128 + d];
        #pragma unroll
        for (int r = 0; r < 8; ++r) acc[r] += sIn[r][k] * wv;
    }

    const float a1 = a[d], a2 = a[128 + d];
    const int wv = d >> 6;
    #pragma unroll
    for (int r = 0; r < 8; ++r) {
        hb[(size_t)(r0 + r) * 128 + d] = (__bf16)acc[r];
        float t1 = acc[r] * a1;
        float t2 = acc[r] * a2;
        #pragma unroll
        for (int m = 1; m < 64; m <<= 1) {
            t1 += __shfl_xor(t1, m);
            t2 += __shfl_xor(t2, m);
        }
        if ((d & 63) == 0) { sRed[r][wv] = t1; sRed[r][2 + wv] = t2; }
    }
    __syncthreads();
    if (d < 8) {
        f1[r0 + d] = (sRed[d][0] + sRed[d][1]) * LOG2E;
        f2[r0 + d] = (sRed[d][2] + sRed[d][3]) * LOG2E;
    }
}

// ---------------------------------------------------------------------------
// Kernel 2: per-batch max of (prescaled) f1
// ---------------------------------------------------------------------------
__global__ __launch_bounds__(256) void gat_f1max(
    const float* __restrict__ f1, float* __restrict__ f1max)
{
    const int b = blockIdx.x;
    const int t = threadIdx.x;
    float m = -1e30f;
    for (int j = t; j < 2048; j += 256) m = fmaxf(m, f1[b * 2048 + j]);
    #pragma unroll
    for (int k = 1; k < 64; k <<= 1) m = fmaxf(m, __shfl_xor(m, k));
    __shared__ float sm[4];
    if ((t & 63) == 0) sm[t >> 6] = m;
    __syncthreads();
    if (t == 0) f1max[b] = fmaxf(fmaxf(sm[0], sm[1]), fmaxf(sm[2], sm[3]));
}

// ---------------------------------------------------------------------------
// Kernel 3: hb (bf16 [b][n][128]) -> pack: fragment-major bf16 B-operands.
// pack elem offset = (b*32 + jt)*8192 + frag*512 + lane*8, frag = D*2 + jh.
// Fragment lane(il,kg) elem e = h[jt*64 + jh*32 + kg*8 + e][D*16 + il].
// ---------------------------------------------------------------------------
__global__ __launch_bounds__(256) void gat_pack(
    const __bf16* __restrict__ hb, __bf16* __restrict__ pack)
{
    __shared__ __bf16 tile[64][72];
    const int tid = threadIdx.x;
    const int bidx = blockIdx.x;         // 512 blocks
    const int b  = bidx >> 6;
    const int tI = bidx & 63;
    const int n0 = (tI >> 1) << 6;       // j-range 64
    const int d0 = (tI & 1) << 6;        // d-range 64
    #pragma unroll
    for (int pass = 0; pass < 2; ++pass) {
        int row = (tid >> 3) + (pass << 5);
        int c   = (tid & 7) << 3;
        *(bf16x8*)&tile[row][c] =
            *(const bf16x8*)(hb + (size_t)(b * 2048 + n0 + row) * 128 + d0 + c);
    }
    __syncthreads();
    const int lane = tid & 63;
    const int il = lane & 15;
    const int kg = lane >> 4;
    #pragma unroll
    for (int pass = 0; pass < 2; ++pass) {
        const int f  = (tid >> 6) + (pass << 2);
        const int Dl = f >> 1;
        const int jh = f & 1;
        union { __bf16 e[8]; bf16x8 v; } u;
        #pragma unroll
        for (int e = 0; e < 8; ++e)
            u.e[e] = tile[(jh << 5) + (kg << 3) + e][(Dl << 4) + il];
        const size_t off = (((size_t)(b << 5) + (n0 >> 6)) << 13)
                         + ((size_t)((((d0 >> 4) + Dl) << 1) | jh) << 9)
                         + (lane << 3);
        *(bf16x8*)(pack + off) = u.v;
    }
}

// ---------------------------------------------------------------------------
// Kernel 4 v14: v13 panel-amortized structure + DEEP counted-vmcnt pipeline.
// Grid 512 = 8 batch x 16 rowgroups(128 rows) x 4 j-quarters; 512 thr (8 waves).
// adj 4-deep (consume slot t&3 loaded 4 iters ago -> vmcnt(10) counted);
// B 3-ahead via sg[2] rotation, stage-write FIRST in iter (waits only the
// oldest load). vmcnt never drains; lgkm-only barrier; setprio around MFMA.
// ---------------------------------------------------------------------------
__global__ __launch_bounds__(512, 4) void gat_attn14(
    const int* __restrict__ adj, const __bf16* __restrict__ pack,
    const float* __restrict__ f1g, const float* __restrict__ f2g,
    const float* __restrict__ f1maxg,
    float* __restrict__ out, __bf16* __restrict__ pO, float* __restrict__ pD)
{
    const int bid = ((blockIdx.x & 7) << 6) | (blockIdx.x >> 3);  // batch<->XCD
    const int b  = bid >> 6;
    const int rg = (bid >> 2) & 15;
    const int jq = bid & 3;
    const int i0 = rg << 7;              // 128 rows per block
    const int jb = jq << 9;              // 512-j quarter
    const int tid = threadIdx.x;

    __shared__ float us[512];            // 2^f1 slice       (2 KB)
    __shared__ float vs[512];            // 2^(0.2 f1) slice (2 KB)
    __shared__ alignas(16) __bf16 Bs[2][4096];   // B tile dbuf (2 x 8 KB)

    const int w    = tid >> 6;           // wave 0..7 -> rows w*16..+16
    const int lane = tid & 63;
    const int il   = lane & 15;
    const int kg   = lane >> 4;

    // ---- issue order matters: f1 slice first, then B, then adj ----
    float4 fvl;
    if (tid < 128) fvl = *(const float4*)&f1g[(b << 11) + jb + (tid << 2)];

    // stage base: wave w stages fragment D=w; frag offset(t) =
    // ((t>>1)<<13) + ((t&1)<<9) relative to (b,jq) base.
    const __bf16* pkB = pack + (((size_t)(b << 5) + (jq << 3)) << 13)
                      + ((w << 1) << 9) + (lane << 3);
    bf16x8 b0  = *(const bf16x8*)(pkB);            // B(0)
    bf16x8 sg1 = *(const bf16x8*)(pkB + 512);      // B(1): ((1>>1)<<13)+((1&1)<<9)
    bf16x8 sg0 = *(const bf16x8*)(pkB + 8192);     // B(2): ((2>>1)<<13)+0

    // adj base: lane covers j = jb + t*32 + kg*8 .. +8 for row i0+w*16+il
    const int row = i0 + (w << 4) + il;
    const int* ap = adj + (((size_t)(b << 11) + row) << 11) + jb + (kg << 3);
    int4 ax[4], ay[4];
    ax[0] = *(const int4*)(ap);       ay[0] = *(const int4*)(ap + 4);
    ax[1] = *(const int4*)(ap + 32);  ay[1] = *(const int4*)(ap + 36);
    ax[2] = *(const int4*)(ap + 64);  ay[2] = *(const int4*)(ap + 68);
    ax[3] = *(const int4*)(ap + 96);  ay[3] = *(const int4*)(ap + 100);

    // j-side tables (consumes fvl -> waits only the f1 load)
    if (tid < 128) {
        float4 uu, vv;
        uu.x = fexp2(fvl.x); uu.y = fexp2(fvl.y);
        uu.z = fexp2(fvl.z); uu.w = fexp2(fvl.w);
        vv.x = fexp2(LRELU_ALPHA * fvl.x); vv.y = fexp2(LRELU_ALPHA * fvl.y);
        vv.z = fexp2(LRELU_ALPHA * fvl.z); vv.w = fexp2(LRELU_ALPHA * fvl.w);
        *(float4*)&us[tid << 2] = uu;
        *(float4*)&vs[tid << 2] = vv;
    }

    // per-lane P factors
    const float fm  = f1maxg[b];
    const float f2v = f2g[(b << 11) + row];
    const float zM  = f2v + fm;
    const float M   = fmaxf(zM, LRELU_ALPHA * zM);        // exact: p <= 1
    const float ai_ = fexp2(f2v - M);
    const float bi_ = fexp2(__builtin_fmaf(LRELU_ALPHA, f2v, -M));

    f32x4 acc[8];
    #pragma unroll
    for (int D = 0; D < 8; ++D) acc[D] = (f32x4){0.f, 0.f, 0.f, 0.f};
    f32x4 accd = {0.f, 0.f, 0.f, 0.f};
    union { __bf16 e[8]; bf16x8 v; } ones;
    #pragma unroll
    for (int x = 0; x < 8; ++x) ones.e[x] = (__bf16)1.0f;
    const bf16x8 onesv = ones.v;

    // stage B(0) (waits only b0: everything else issued after it)
    *(bf16x8*)&Bs[0][(w << 9) + (lane << 3)] = b0;

    wg_barrier();                                  // us/vs + Bs[0] ready

    #pragma unroll
    for (int t = 0; t < 16; ++t) {
        const int cb = t & 1;

        // ---- 1. stage-write B(t+1) (load issued at t-2; oldest in flight) --
        if (t < 15) {
            *(bf16x8*)&Bs[cb ^ 1][(w << 9) + (lane << 3)] = (((t + 1) & 1) ? sg1 : sg0);
        }
        // ---- 2. issue B(t+3) into the freed slot ----
        if (t + 3 <= 15) {
            bf16x8 nb = *(const bf16x8*)(pkB + (((t + 3) >> 1) << 13) + (((t + 3) & 1) << 9));
            if (((t + 1) & 1)) sg1 = nb; else sg0 = nb;
        }

        // ---- 3. P(t): consume adj slot t&3 (loaded 4 iters ago) ----
        const int4 axv = ax[t & 3];
        const int4 ayv = ay[t & 3];
        const float4 u0 = *(const float4*)&us[t * 32 + (kg << 3)];
        const float4 u1 = *(const float4*)&us[t * 32 + (kg << 3) + 4];
        const float4 v0 = *(const float4*)&vs[t * 32 + (kg << 3)];
        const float4 v1 = *(const float4*)&vs[t * 32 + (kg << 3) + 4];
        union { __bf16 e[8]; bf16x8 v; } pa;
        pa.e[0] = (axv.x > 0) ? (__bf16)fmaxf(ai_ * u0.x, bi_ * v0.x) : (__bf16)0.f;
        pa.e[1] = (axv.y > 0) ? (__bf16)fmaxf(ai_ * u0.y, bi_ * v0.y) : (__bf16)0.f;
        pa.e[2] = (axv.z > 0) ? (__bf16)fmaxf(ai_ * u0.z, bi_ * v0.z) : (__bf16)0.f;
        pa.e[3] = (axv.w > 0) ? (__bf16)fmaxf(ai_ * u0.w, bi_ * v0.w) : (__bf16)0.f;
        pa.e[4] = (ayv.x > 0) ? (__bf16)fmaxf(ai_ * u1.x, bi_ * v1.x) : (__bf16)0.f;
        pa.e[5] = (ayv.y > 0) ? (__bf16)fmaxf(ai_ * u1.y, bi_ * v1.y) : (__bf16)0.f;
        pa.e[6] = (ayv.z > 0) ? (__bf16)fmaxf(ai_ * u1.z, bi_ * v1.z) : (__bf16)0.f;
        pa.e[7] = (ayv.w > 0) ? (__bf16)fmaxf(ai_ * u1.w, bi_ * v1.w) : (__bf16)0.f;

        // ---- 4. refill adj slot with tile t+4 (stays 4-deep) ----
        if (t + 4 < 16) {
            ax[t & 3] = *(const int4*)(ap + (t + 4) * 32);
            ay[t & 3] = *(const int4*)(ap + (t + 4) * 32 + 4);
        }

        // ---- 5. ds_read/MFMA interleave under raised priority ----
        __builtin_amdgcn_s_setprio(1);
        #pragma unroll
        for (int D = 0; D < 8; ++D) {
            bf16x8 Bf = *(const bf16x8*)&Bs[cb][(D << 9) + (lane << 3)];
            acc[D] = __builtin_amdgcn_mfma_f32_16x16x32_bf16(pa.v, Bf, acc[D], 0, 0, 0);
        }
        accd = __builtin_amdgcn_mfma_f32_16x16x32_bf16(pa.v, onesv, accd, 0, 0, 0);
        __builtin_amdgcn_s_setprio(0);

        // ---- 6. lgkm-only barrier (global prefetches stay in flight) ----
        if (t < 15) wg_barrier();
    }

    // ---- write partials: C row = kg*4+r, col = il (+ D*16) ----
    const int rowg = (b << 11) + i0 + (w << 4) + (kg << 2);
    if (jq == 0) {
        #pragma unroll
        for (int r = 0; r < 4; ++r) {
            const size_t base = (((size_t)rowg + r) << 7) + il;
            #pragma unroll
            for (int D = 0; D < 8; ++D)
                out[base + (D << 4)] = acc[D][r];
        }
    } else {
        __bf16* po = pO + ((size_t)(jq - 1) << 21);
        #pragma unroll
        for (int r = 0; r < 4; ++r) {
            const size_t base = (((size_t)rowg + r) << 7) + il;
            #pragma unroll
            for (int D = 0; D < 8; ++D)
                po[base + (D << 4)] = (__bf16)acc[D][r];
        }
    }
    if (il == 0) {
        #pragma unroll
        for (int r = 0; r < 4; ++r)
            pD[(jq << 14) + rowg + r] = accd[r];
    }
}

// ---------------------------------------------------------------------------
// Kernel 5: combine 4 j-quarter partials, normalize, elu, residual.
// io aliases out (jq=0 partial): read-before-write per element, same thread.
// ---------------------------------------------------------------------------
__global__ __launch_bounds__(256) void gat_combine(
    float* io, const __bf16* __restrict__ pO,
    const float* __restrict__ pD, const __bf16* __restrict__ hb)
{
    const int idx = blockIdx.x * 256 + threadIdx.x;    // 0..262143
    const size_t base = (size_t)idx << 3;
    const int rowAll = idx >> 4;                       // 16 threads per 128-row
    const float den = pD[rowAll] + pD[16384 + rowAll]
                    + pD[32768 + rowAll] + pD[49152 + rowAll];
    const float rden = 1.0f / den;
    float4 o0a = *(const float4*)(io + base);
    float4 o0b = *(const float4*)(io + base + 4);
    bf16x8 p1 = *(const bf16x8*)(pO + base);
    bf16x8 p2 = *(const bf16x8*)(pO + (1u << 21) + base);
    bf16x8 p3 = *(const bf16x8*)(pO + (2u << 21) + base);
    bf16x8 hv = *(const bf16x8*)(hb + base);
    float res[8];
    #pragma unroll
    for (int e = 0; e < 8; ++e) {
        float o = ((e < 4) ? ((const float*)&o0a)[e] : ((const float*)&o0b)[e - 4])
                + (float)p1[e] + (float)p2[e] + (float)p3[e];
        float v  = o * rden;
        float el = (v > 0.f) ? v : (fexp2(v * LOG2E) - 1.f);
        res[e] = el + (float)hv[e];
    }
    *(float4*)(io + base)     = (float4){res[0], res[1], res[2], res[3]};
    *(float4*)(io + base + 4) = (float4){res[4], res[5], res[6], res[7]};
}

// ---------------------------------------------------------------------------
extern "C" void kernel_launch(void* const* d_in, const int* in_sizes, int n_in,
                              void* d_out, int out_size, void* d_ws, size_t ws_size,
                              hipStream_t stream)
{
    const float* inp = (const float*)d_in[0];
    const int*   adj = (const int*)d_in[1];
    const float* W   = (const float*)d_in[2];
    const float* a   = (const float*)d_in[3];
    float* out = (float*)d_out;

    // workspace layout (~20.5 MB)
    char* ws = (char*)d_ws;
    __bf16* hb    = (__bf16*)ws;                          // 4 MB
    __bf16* pack  = (__bf16*)(ws + (4 << 20));            // 4 MB
    __bf16* pO    = (__bf16*)(ws + (8 << 20));            // 12 MB (3 bf16 partials)
    float*  pD    = (float*)(ws + (20 << 20));            // 256 KB (4 x 16384)
    float*  f1    = (float*)(ws + (20 << 20) + 262144);   // 64 KB
    float*  f2    = (float*)(ws + (20 << 20) + 262144 + 65536);
    float*  f1max = (float*)(ws + (20 << 20) + 262144 + 131072);

    gat_prep<<<2048, 128, 0, stream>>>(inp, W, a, hb, f1, f2);
    gat_f1max<<<8, 256, 0, stream>>>(f1, f1max);
    gat_pack<<<512, 256, 0, stream>>>(hb, pack);
    gat_attn14<<<512, 512, 0, stream>>>(adj, pack, f1, f2, f1max, out, pO, pD);
    gat_combine<<<1024, 256, 0, stream>>>(out, pO, pD, hb);
}

// Round 15
// 64.095 us; speedup vs baseline: 1.0004x; 1.0004x over previous
//
#include <hip/hip_runtime.h>
#include <hip/hip_bf16.h>

typedef __bf16 bf16x8 __attribute__((ext_vector_type(8)));
typedef float  f32x4  __attribute__((ext_vector_type(4)));

#define LRELU_ALPHA 0.2f
#define LOG2E 1.44269504088896340736f

// native 2^x (single v_exp_f32, no OCML call)
__device__ __forceinline__ float fexp2(float x) {
#if __has_builtin(__builtin_amdgcn_exp2f)
    return __builtin_amdgcn_exp2f(x);
#else
    float r; asm("v_exp_f32 %0, %1" : "=v"(r) : "v"(x)); return r;
#endif
}

// raw barrier: drains LDS (lgkmcnt) but leaves global prefetches (vmcnt) in flight
__device__ __forceinline__ void wg_barrier() {
    asm volatile("s_waitcnt lgkmcnt(0)" ::: "memory");
    __builtin_amdgcn_s_barrier();
    asm volatile("" ::: "memory");
}

// ---------------------------------------------------------------------------
// Kernel 1: h = inp @ W (8 rows/block) -> hb (bf16), f1 = log2e*(h·a1),
// f2 = log2e*(h·a2).
// ---------------------------------------------------------------------------
__global__ __launch_bounds__(128) void gat_prep(
    const float* __restrict__ inp, const float* __restrict__ W,
    const float* __restrict__ a,
    __bf16* __restrict__ hb, float* __restrict__ f1, float* __restrict__ f2)
{
    const int r0 = blockIdx.x << 3;
    const int d  = threadIdx.x;
    __shared__ float sIn[8][128];
    __shared__ float sRed[8][4];
    #pragma unroll
    for (int r = 0; r < 8; ++r)
        sIn[r][d] = inp[(size_t)(r0 + r) * 128 + d];
    __syncthreads();

    float acc[8] = {0.f,0.f,0.f,0.f,0.f,0.f,0.f,0.f};
    #pragma unroll 4
    for (int k = 0; k < 128; ++k) {
        float wv = W[k * 128 + d];
        #pragma unroll
        for (int r = 0; r < 8; ++r) acc[r] += sIn[r][k] * wv;
    }

    const float a1 = a[d], a2 = a[128 + d];
    const int wv = d >> 6;
    #pragma unroll
    for (int r = 0; r < 8; ++r) {
        hb[(size_t)(r0 + r) * 128 + d] = (__bf16)acc[r];
        float t1 = acc[r] * a1;
        float t2 = acc[r] * a2;
        #pragma unroll
        for (int m = 1; m < 64; m <<= 1) {
            t1 += __shfl_xor(t1, m);
            t2 += __shfl_xor(t2, m);
        }
        if ((d & 63) == 0) { sRed[r][wv] = t1; sRed[r][2 + wv] = t2; }
    }
    __syncthreads();
    if (d < 8) {
        f1[r0 + d] = (sRed[d][0] + sRed[d][1]) * LOG2E;
        f2[r0 + d] = (sRed[d][2] + sRed[d][3]) * LOG2E;
    }
}

// ---------------------------------------------------------------------------
// Kernel 2: per-batch max of (prescaled) f1
// ---------------------------------------------------------------------------
__global__ __launch_bounds__(256) void gat_f1max(
    const float* __restrict__ f1, float* __restrict__ f1max)
{
    const int b = blockIdx.x;
    const int t = threadIdx.x;
    float m = -1e30f;
    for (int j = t; j < 2048; j += 256) m = fmaxf(m, f1[b * 2048 + j]);
    #pragma unroll
    for (int k = 1; k < 64; k <<= 1) m = fmaxf(m, __shfl_xor(m, k));
    __shared__ float sm[4];
    if ((t & 63) == 0) sm[t >> 6] = m;
    __syncthreads();
    if (t == 0) f1max[b] = fmaxf(fmaxf(sm[0], sm[1]), fmaxf(sm[2], sm[3]));
}

// ---------------------------------------------------------------------------
// Kernel 3: hb (bf16 [b][n][128]) -> pack: fragment-major bf16 B-operands.
// pack elem offset = (b*32 + jt)*8192 + frag*512 + lane*8, frag = D*2 + jh.
// Fragment lane(il,kg) elem e = h[jt*64 + jh*32 + kg*8 + e][D*16 + il].
// ---------------------------------------------------------------------------
__global__ __launch_bounds__(256) void gat_pack(
    const __bf16* __restrict__ hb, __bf16* __restrict__ pack)
{
    __shared__ __bf16 tile[64][72];
    const int tid = threadIdx.x;
    const int bidx = blockIdx.x;         // 512 blocks
    const int b  = bidx >> 6;
    const int tI = bidx & 63;
    const int n0 = (tI >> 1) << 6;       // j-range 64
    const int d0 = (tI & 1) << 6;        // d-range 64
    #pragma unroll
    for (int pass = 0; pass < 2; ++pass) {
        int row = (tid >> 3) + (pass << 5);
        int c   = (tid & 7) << 3;
        *(bf16x8*)&tile[row][c] =
            *(const bf16x8*)(hb + (size_t)(b * 2048 + n0 + row) * 128 + d0 + c);
    }
    __syncthreads();
    const int lane = tid & 63;
    const int il = lane & 15;
    const int kg = lane >> 4;
    #pragma unroll
    for (int pass = 0; pass < 2; ++pass) {
        const int f  = (tid >> 6) + (pass << 2);
        const int Dl = f >> 1;
        const int jh = f & 1;
        union { __bf16 e[8]; bf16x8 v; } u;
        #pragma unroll
        for (int e = 0; e < 8; ++e)
            u.e[e] = tile[(jh << 5) + (kg << 3) + e][(Dl << 4) + il];
        const size_t off = (((size_t)(b << 5) + (n0 >> 6)) << 13)
                         + ((size_t)((((d0 >> 4) + Dl) << 1) | jh) << 9)
                         + (lane << 3);
        *(bf16x8*)(pack + off) = u.v;
    }
}

// ---------------------------------------------------------------------------
// Kernel 4 v14: v13 panel-amortized structure + DEEP counted-vmcnt pipeline.
// Grid 512 = 8 batch x 16 rowgroups(128 rows) x 4 j-quarters; 512 thr (8 waves).
// adj 4-deep (consume slot t&3 loaded 4 iters ago -> vmcnt(10) counted);
// B 3-ahead via sg[2] rotation, stage-write FIRST in iter (waits only the
// oldest load). vmcnt never drains; lgkm-only barrier; setprio around MFMA.
// ---------------------------------------------------------------------------
__global__ __launch_bounds__(512, 4) void gat_attn14(
    const int* __restrict__ adj, const __bf16* __restrict__ pack,
    const float* __restrict__ f1g, const float* __restrict__ f2g,
    const float* __restrict__ f1maxg,
    float* __restrict__ out, __bf16* __restrict__ pO, float* __restrict__ pD)
{
    const int bid = ((blockIdx.x & 7) << 6) | (blockIdx.x >> 3);  // batch<->XCD
    const int b  = bid >> 6;
    const int rg = (bid >> 2) & 15;
    const int jq = bid & 3;
    const int i0 = rg << 7;              // 128 rows per block
    const int jb = jq << 9;              // 512-j quarter
    const int tid = threadIdx.x;

    __shared__ float us[512];            // 2^f1 slice       (2 KB)
    __shared__ float vs[512];            // 2^(0.2 f1) slice (2 KB)
    __shared__ alignas(16) __bf16 Bs[2][4096];   // B tile dbuf (2 x 8 KB)

    const int w    = tid >> 6;           // wave 0..7 -> rows w*16..+16
    const int lane = tid & 63;
    const int il   = lane & 15;
    const int kg   = lane >> 4;

    // ---- issue order matters: f1 slice first, then B, then adj ----
    float4 fvl;
    if (tid < 128) fvl = *(const float4*)&f1g[(b << 11) + jb + (tid << 2)];

    // stage base: wave w stages fragment D=w; frag offset(t) =
    // ((t>>1)<<13) + ((t&1)<<9) relative to (b,jq) base.
    const __bf16* pkB = pack + (((size_t)(b << 5) + (jq << 3)) << 13)
                      + ((w << 1) << 9) + (lane << 3);
    bf16x8 b0  = *(const bf16x8*)(pkB);            // B(0)
    bf16x8 sg1 = *(const bf16x8*)(pkB + 512);      // B(1): ((1>>1)<<13)+((1&1)<<9)
    bf16x8 sg0 = *(const bf16x8*)(pkB + 8192);     // B(2): ((2>>1)<<13)+0

    // adj base: lane covers j = jb + t*32 + kg*8 .. +8 for row i0+w*16+il
    const int row = i0 + (w << 4) + il;
    const int* ap = adj + (((size_t)(b << 11) + row) << 11) + jb + (kg << 3);
    int4 ax[4], ay[4];
    ax[0] = *(const int4*)(ap);       ay[0] = *(const int4*)(ap + 4);
    ax[1] = *(const int4*)(ap + 32);  ay[1] = *(const int4*)(ap + 36);
    ax[2] = *(const int4*)(ap + 64);  ay[2] = *(const int4*)(ap + 68);
    ax[3] = *(const int4*)(ap + 96);  ay[3] = *(const int4*)(ap + 100);

    // j-side tables (consumes fvl -> waits only the f1 load)
    if (tid < 128) {
        float4 uu, vv;
        uu.x = fexp2(fvl.x); uu.y = fexp2(fvl.y);
        uu.z = fexp2(fvl.z); uu.w = fexp2(fvl.w);
        vv.x = fexp2(LRELU_ALPHA * fvl.x); vv.y = fexp2(LRELU_ALPHA * fvl.y);
        vv.z = fexp2(LRELU_ALPHA * fvl.z); vv.w = fexp2(LRELU_ALPHA * fvl.w);
        *(float4*)&us[tid << 2] = uu;
        *(float4*)&vs[tid << 2] = vv;
    }

    // per-lane P factors
    const float fm  = f1maxg[b];
    const float f2v = f2g[(b << 11) + row];
    const float zM  = f2v + fm;
    const float M   = fmaxf(zM, LRELU_ALPHA * zM);        // exact: p <= 1
    const float ai_ = fexp2(f2v - M);
    const float bi_ = fexp2(__builtin_fmaf(LRELU_ALPHA, f2v, -M));

    f32x4 acc[8];
    #pragma unroll
    for (int D = 0; D < 8; ++D) acc[D] = (f32x4){0.f, 0.f, 0.f, 0.f};
    f32x4 accd = {0.f, 0.f, 0.f, 0.f};
    union { __bf16 e[8]; bf16x8 v; } ones;
    #pragma unroll
    for (int x = 0; x < 8; ++x) ones.e[x] = (__bf16)1.0f;
    const bf16x8 onesv = ones.v;

    // stage B(0) (waits only b0: everything else issued after it)
    *(bf16x8*)&Bs[0][(w << 9) + (lane << 3)] = b0;

    wg_barrier();                                  // us/vs + Bs[0] ready

    #pragma unroll
    for (int t = 0; t < 16; ++t) {
        const int cb = t & 1;

        // ---- 1. stage-write B(t+1) (load issued at t-2; oldest in flight) --
        if (t < 15) {
            *(bf16x8*)&Bs[cb ^ 1][(w << 9) + (lane << 3)] = (((t + 1) & 1) ? sg1 : sg0);
        }
        // ---- 2. issue B(t+3) into the freed slot ----
        if (t + 3 <= 15) {
            bf16x8 nb = *(const bf16x8*)(pkB + (((t + 3) >> 1) << 13) + (((t + 3) & 1) << 9));
            if (((t + 1) & 1)) sg1 = nb; else sg0 = nb;
        }

        // ---- 3. P(t): consume adj slot t&3 (loaded 4 iters ago) ----
        const int4 axv = ax[t & 3];
        const int4 ayv = ay[t & 3];
        const float4 u0 = *(const float4*)&us[t * 32 + (kg << 3)];
        const float4 u1 = *(const float4*)&us[t * 32 + (kg << 3) + 4];
        const float4 v0 = *(const float4*)&vs[t * 32 + (kg << 3)];
        const float4 v1 = *(const float4*)&vs[t * 32 + (kg << 3) + 4];
        union { __bf16 e[8]; bf16x8 v; } pa;
        pa.e[0] = (axv.x > 0) ? (__bf16)fmaxf(ai_ * u0.x, bi_ * v0.x) : (__bf16)0.f;
        pa.e[1] = (axv.y > 0) ? (__bf16)fmaxf(ai_ * u0.y, bi_ * v0.y) : (__bf16)0.f;
        pa.e[2] = (axv.z > 0) ? (__bf16)fmaxf(ai_ * u0.z, bi_ * v0.z) : (__bf16)0.f;
        pa.e[3] = (axv.w > 0) ? (__bf16)fmaxf(ai_ * u0.w, bi_ * v0.w) : (__bf16)0.f;
        pa.e[4] = (ayv.x > 0) ? (__bf16)fmaxf(ai_ * u1.x, bi_ * v1.x) : (__bf16)0.f;
        pa.e[5] = (ayv.y > 0) ? (__bf16)fmaxf(ai_ * u1.y, bi_ * v1.y) : (__bf16)0.f;
        pa.e[6] = (ayv.z > 0) ? (__bf16)fmaxf(ai_ * u1.z, bi_ * v1.z) : (__bf16)0.f;
        pa.e[7] = (ayv.w > 0) ? (__bf16)fmaxf(ai_ * u1.w, bi_ * v1.w) : (__bf16)0.f;

        // ---- 4. refill adj slot with tile t+4 (stays 4-deep) ----
        if (t + 4 < 16) {
            ax[t & 3] = *(const int4*)(ap + (t + 4) * 32);
            ay[t & 3] = *(const int4*)(ap + (t + 4) * 32 + 4);
        }

        // ---- 5. ds_read/MFMA interleave under raised priority ----
        __builtin_amdgcn_s_setprio(1);
        #pragma unroll
        for (int D = 0; D < 8; ++D) {
            bf16x8 Bf = *(const bf16x8*)&Bs[cb][(D << 9) + (lane << 3)];
            acc[D] = __builtin_amdgcn_mfma_f32_16x16x32_bf16(pa.v, Bf, acc[D], 0, 0, 0);
        }
        accd = __builtin_amdgcn_mfma_f32_16x16x32_bf16(pa.v, onesv, accd, 0, 0, 0);
        __builtin_amdgcn_s_setprio(0);

        // ---- 6. lgkm-only barrier (global prefetches stay in flight) ----
        if (t < 15) wg_barrier();
    }

    // ---- write partials: C row = kg*4+r, col = il (+ D*16) ----
    const int rowg = (b << 11) + i0 + (w << 4) + (kg << 2);
    if (jq == 0) {
        #pragma unroll
        for (int r = 0; r < 4; ++r) {
            const size_t base = (((size_t)rowg + r) << 7) + il;
            #pragma unroll
            for (int D = 0; D < 8; ++D)
                out[base + (D << 4)] = acc[D][r];
        }
    } else {
        __bf16* po = pO + ((size_t)(jq - 1) << 21);
        #pragma unroll
        for (int r = 0; r < 4; ++r) {
            const size_t base = (((size_t)rowg + r) << 7) + il;
            #pragma unroll
            for (int D = 0; D < 8; ++D)
                po[base + (D << 4)] = (__bf16)acc[D][r];
        }
    }
    if (il == 0) {
        #pragma unroll
        for (int r = 0; r < 4; ++r)
            pD[(jq << 14) + rowg + r] = accd[r];
    }
}

// ---------------------------------------------------------------------------
// Kernel 5: combine 4 j-quarter partials, normalize, elu, residual.
// io aliases out (jq=0 partial): read-before-write per element, same thread.
// ---------------------------------------------------------------------------
__global__ __launch_bounds__(256) void gat_combine(
    float* io, const __bf16* __restrict__ pO,
    const float* __restrict__ pD, const __bf16* __restrict__ hb)
{
    const int idx = blockIdx.x * 256 + threadIdx.x;    // 0..262143
    const size_t base = (size_t)idx << 3;
    const int rowAll = idx >> 4;                       // 16 threads per 128-row
    const float den = pD[rowAll] + pD[16384 + rowAll]
                    + pD[32768 + rowAll] + pD[49152 + rowAll];
    const float rden = 1.0f / den;
    float4 o0a = *(const float4*)(io + base);
    float4 o0b = *(const float4*)(io + base + 4);
    bf16x8 p1 = *(const bf16x8*)(pO + base);
    bf16x8 p2 = *(const bf16x8*)(pO + (1u << 21) + base);
    bf16x8 p3 = *(const bf16x8*)(pO + (2u << 21) + base);
    bf16x8 hv = *(const bf16x8*)(hb + base);
    float res[8];
    #pragma unroll
    for (int e = 0; e < 8; ++e) {
        float o = ((e < 4) ? ((const float*)&o0a)[e] : ((const float*)&o0b)[e - 4])
                + (float)p1[e] + (float)p2[e] + (float)p3[e];
        float v  = o * rden;
        float el = (v > 0.f) ? v : (fexp2(v * LOG2E) - 1.f);
        res[e] = el + (float)hv[e];
    }
    *(float4*)(io + base)     = (float4){res[0], res[1], res[2], res[3]};
    *(float4*)(io + base + 4) = (float4){res[4], res[5], res[6], res[7]};
}

// ---------------------------------------------------------------------------
extern "C" void kernel_launch(void* const* d_in, const int* in_sizes, int n_in,
                              void* d_out, int out_size, void* d_ws, size_t ws_size,
                              hipStream_t stream)
{
    const float* inp = (const float*)d_in[0];
    const int*   adj = (const int*)d_in[1];
    const float* W   = (const float*)d_in[2];
    const float* a   = (const float*)d_in[3];
    float* out = (float*)d_out;

    // workspace layout (~20.5 MB)
    char* ws = (char*)d_ws;
    __bf16* hb    = (__bf16*)ws;                          // 4 MB
    __bf16* pack  = (__bf16*)(ws + (4 << 20));            // 4 MB
    __bf16* pO    = (__bf16*)(ws + (8 << 20));            // 12 MB (3 bf16 partials)
    float*  pD    = (float*)(ws + (20 << 20));            // 256 KB (4 x 16384)
    float*  f1    = (float*)(ws + (20 << 20) + 262144);   // 64 KB
    float*  f2    = (float*)(ws + (20 << 20) + 262144 + 65536);
    float*  f1max = (float*)(ws + (20 << 20) + 262144 + 131072);

    gat_prep<<<2048, 128, 0, stream>>>(inp, W, a, hb, f1, f2);
    gat_f1max<<<8, 256, 0, stream>>>(f1, f1max);
    gat_pack<<<512, 256, 0, stream>>>(hb, pack);
    gat_attn14<<<512, 512, 0, stream>>>(adj, pack, f1, f2, f1max, out, pO, pD);
    gat_combine<<<1024, 256, 0, stream>>>(out, pO, pD, hb);
}